// Round 1
// baseline (2199.577 us; speedup 1.0000x reference)
//
#include <hip/hip_runtime.h>
#include <math.h>

#define NROWS  16384   // B*S
#define DMODEL 1024
#define NHEAD  16
#define HDIM   64
#define SEQ    4096
#define NBATCH 4
#define NBH    64      // NBATCH*NHEAD
#define SCHUNK 8       // split-K chunks over S for kv aggregation

// ---------------------------------------------------------------------------
// GEMM (NT): C[m,n] = sum_d A[m,d] * W[n,d] + bias[n]; optional elu(x)+1.
// Tile 128x128, K-step 32. 256 threads, 8x8 microtile per thread.
// LDS stride 33: a-reads broadcast over tx (free), b-reads 2-way (free).
// ---------------------------------------------------------------------------
template<int ELU>
__global__ __launch_bounds__(256)
void gemm_nt(const float* __restrict__ A, const float* __restrict__ W,
             const float* __restrict__ bias, float* __restrict__ C)
{
    __shared__ float As[128][33];
    __shared__ float Bs[128][33];
    const int t  = threadIdx.x;
    const int tx = t & 15;
    const int ty = t >> 4;
    const int m0 = blockIdx.x * 128;
    const int n0 = blockIdx.y * 128;

    float acc[8][8];
#pragma unroll
    for (int i = 0; i < 8; ++i)
#pragma unroll
        for (int j = 0; j < 8; ++j) acc[i][j] = 0.f;

    for (int k0 = 0; k0 < DMODEL; k0 += 32) {
        // stage A and B tiles: 128 rows x 32 k each, float4-coalesced
#pragma unroll
        for (int i = 0; i < 4; ++i) {
            const int idx = i * 256 + t;
            const int row = idx >> 3;
            const int c4  = (idx & 7) * 4;
            const float4 va = *(const float4*)&A[(size_t)(m0 + row) * DMODEL + k0 + c4];
            As[row][c4 + 0] = va.x; As[row][c4 + 1] = va.y;
            As[row][c4 + 2] = va.z; As[row][c4 + 3] = va.w;
            const float4 vb = *(const float4*)&W[(size_t)(n0 + row) * DMODEL + k0 + c4];
            Bs[row][c4 + 0] = vb.x; Bs[row][c4 + 1] = vb.y;
            Bs[row][c4 + 2] = vb.z; Bs[row][c4 + 3] = vb.w;
        }
        __syncthreads();

#pragma unroll 4
        for (int k = 0; k < 32; ++k) {
            float a[8], b[8];
#pragma unroll
            for (int i = 0; i < 8; ++i) a[i] = As[(i >> 2) * 64 + ty * 4 + (i & 3)][k];
#pragma unroll
            for (int j = 0; j < 8; ++j) b[j] = Bs[(j >> 2) * 64 + tx * 4 + (j & 3)][k];
#pragma unroll
            for (int i = 0; i < 8; ++i)
#pragma unroll
                for (int j = 0; j < 8; ++j)
                    acc[i][j] = fmaf(a[i], b[j], acc[i][j]);
        }
        __syncthreads();
    }

    // epilogue: bias (+ optional elu(x)+1), float4 stores
#pragma unroll
    for (int i = 0; i < 8; ++i) {
        const int m = m0 + (i >> 2) * 64 + ty * 4 + (i & 3);
#pragma unroll
        for (int jh = 0; jh < 2; ++jh) {
            const int n = n0 + jh * 64 + tx * 4;
            float rv[4];
#pragma unroll
            for (int jj = 0; jj < 4; ++jj) {
                float v = acc[i][jh * 4 + jj] + bias[n + jj];
                if (ELU) v = (v > 0.f) ? (v + 1.f) : __expf(v);  // elu(v)+1
                rv[jj] = v;
            }
            float4 o; o.x = rv[0]; o.y = rv[1]; o.z = rv[2]; o.w = rv[3];
            *(float4*)&C[(size_t)m * DMODEL + n] = o;
        }
    }
}

// ---------------------------------------------------------------------------
// kv partials: for (b,h,schunk): kvp[d][e] = sum_{s in chunk} k[s,d]*v[s,e],
// ksp[d] = sum k[s,d]. Deterministic split-K (no atomics).
// grid (NBH, SCHUNK), 256 threads. thread: d = t&63, e-range = (t>>6)*16 .. +15
// ---------------------------------------------------------------------------
__global__ __launch_bounds__(256)
void kv_partial(const float* __restrict__ k, const float* __restrict__ v,
                float* __restrict__ kvp, float* __restrict__ ksp)
{
    __shared__ float Ks[32][64];
    __shared__ float Vs[32][64];
    const int t  = threadIdx.x;
    const int bh = blockIdx.x;           // b*NHEAD + h
    const int b  = bh >> 4;
    const int h  = bh & 15;
    const int sc = blockIdx.y;
    const int d  = t & 63;
    const int e0 = (t >> 6) * 16;

    float acc[16];
#pragma unroll
    for (int j = 0; j < 16; ++j) acc[j] = 0.f;
    float ks = 0.f;

    const size_t rowbase = (size_t)b * SEQ;
    const int sbeg = sc * (SEQ / SCHUNK);
    const int send = sbeg + (SEQ / SCHUNK);

    for (int s0 = sbeg; s0 < send; s0 += 32) {
#pragma unroll
        for (int i = 0; i < 2; ++i) {
            const int idx = i * 256 + t;
            const int row = idx >> 4;
            const int c4  = (idx & 15) * 4;
            const size_t g = (rowbase + s0 + row) * DMODEL + h * HDIM + c4;
            *(float4*)&Ks[row][c4] = *(const float4*)&k[g];
            *(float4*)&Vs[row][c4] = *(const float4*)&v[g];
        }
        __syncthreads();
#pragma unroll
        for (int sp = 0; sp < 32; ++sp) {
            const float kd = Ks[sp][d];
            if (t < 64) ks += Ks[sp][t];
            const float4 v0 = *(const float4*)&Vs[sp][e0 + 0];
            const float4 v1 = *(const float4*)&Vs[sp][e0 + 4];
            const float4 v2 = *(const float4*)&Vs[sp][e0 + 8];
            const float4 v3 = *(const float4*)&Vs[sp][e0 + 12];
            acc[0]  = fmaf(kd, v0.x, acc[0]);  acc[1]  = fmaf(kd, v0.y, acc[1]);
            acc[2]  = fmaf(kd, v0.z, acc[2]);  acc[3]  = fmaf(kd, v0.w, acc[3]);
            acc[4]  = fmaf(kd, v1.x, acc[4]);  acc[5]  = fmaf(kd, v1.y, acc[5]);
            acc[6]  = fmaf(kd, v1.z, acc[6]);  acc[7]  = fmaf(kd, v1.w, acc[7]);
            acc[8]  = fmaf(kd, v2.x, acc[8]);  acc[9]  = fmaf(kd, v2.y, acc[9]);
            acc[10] = fmaf(kd, v2.z, acc[10]); acc[11] = fmaf(kd, v2.w, acc[11]);
            acc[12] = fmaf(kd, v3.x, acc[12]); acc[13] = fmaf(kd, v3.y, acc[13]);
            acc[14] = fmaf(kd, v3.z, acc[14]); acc[15] = fmaf(kd, v3.w, acc[15]);
        }
        __syncthreads();
    }

    const size_t base = ((size_t)sc * NBH + bh) * HDIM;
#pragma unroll
    for (int q = 0; q < 4; ++q) {
        float4 o; o.x = acc[q*4+0]; o.y = acc[q*4+1]; o.z = acc[q*4+2]; o.w = acc[q*4+3];
        *(float4*)&kvp[(base + d) * HDIM + e0 + q * 4] = o;
    }
    if (t < 64) ksp[base + t] = ks;
}

// ---------------------------------------------------------------------------
// Reduce split-K partials: kv = sum_sc kvp, ksum = sum_sc ksp.
// ---------------------------------------------------------------------------
__global__ __launch_bounds__(256)
void kv_reduce(const float* __restrict__ kvp, const float* __restrict__ ksp,
               float* __restrict__ kv, float* __restrict__ ksum)
{
    const int i = blockIdx.x * 256 + threadIdx.x;
    const int NKV = NBH * HDIM * HDIM;  // 262144
    if (i < NKV) {
        float s = 0.f;
#pragma unroll
        for (int c = 0; c < SCHUNK; ++c) s += kvp[(size_t)c * NKV + i];
        kv[i] = s;
    }
    if (i < NBH * HDIM) {
        float s = 0.f;
#pragma unroll
        for (int c = 0; c < SCHUNK; ++c) s += ksp[(size_t)c * NBH * HDIM + i];
        ksum[i] = s;
    }
}

// ---------------------------------------------------------------------------
// att[s,e] = (sum_d q[s,d]*kv[d,e]) / (sum_d q[s,d]*ksum[d] + 1e-6)
// In-place over q. grid (SEQ/64, NBATCH, NHEAD), 256 threads.
// thread: row r = t>>2 (64 rows/block), e-range = (t&3)*16 .. +15
// ---------------------------------------------------------------------------
__global__ __launch_bounds__(256)
void qkv_norm(float* __restrict__ q, const float* __restrict__ kv,
              const float* __restrict__ ksum)
{
    __shared__ float Qs[64][68];
    __shared__ float KVs[64][64];
    __shared__ float kss[64];
    const int t  = threadIdx.x;
    const int s0 = blockIdx.x * 64;
    const int b  = blockIdx.y;
    const int h  = blockIdx.z;
    const int bh = b * NHEAD + h;

#pragma unroll
    for (int i = 0; i < 4; ++i) {
        const int idx = i * 256 + t;
        const int row = idx >> 4;
        const int c4  = (idx & 15) * 4;
        const float4 vq = *(const float4*)&q[((size_t)b * SEQ + s0 + row) * DMODEL + h * HDIM + c4];
        *(float4*)&Qs[row][c4] = vq;   // stride 68 floats = 272B (16B multiple)
        *(float4*)&((float*)KVs)[idx * 4] = *(const float4*)&kv[(size_t)bh * HDIM * HDIM + idx * 4];
    }
    if (t < 64) kss[t] = ksum[(size_t)bh * HDIM + t];
    __syncthreads();

    const int r  = t >> 2;
    const int e0 = (t & 3) * 16;
    float out[16];
#pragma unroll
    for (int j = 0; j < 16; ++j) out[j] = 0.f;
    float nrm = 0.f;

#pragma unroll 8
    for (int d = 0; d < 64; ++d) {
        const float qd = Qs[r][d];
        nrm = fmaf(qd, kss[d], nrm);
        const float4 k0 = *(const float4*)&KVs[d][e0 + 0];
        const float4 k1 = *(const float4*)&KVs[d][e0 + 4];
        const float4 k2 = *(const float4*)&KVs[d][e0 + 8];
        const float4 k3 = *(const float4*)&KVs[d][e0 + 12];
        out[0]  = fmaf(qd, k0.x, out[0]);  out[1]  = fmaf(qd, k0.y, out[1]);
        out[2]  = fmaf(qd, k0.z, out[2]);  out[3]  = fmaf(qd, k0.w, out[3]);
        out[4]  = fmaf(qd, k1.x, out[4]);  out[5]  = fmaf(qd, k1.y, out[5]);
        out[6]  = fmaf(qd, k1.z, out[6]);  out[7]  = fmaf(qd, k1.w, out[7]);
        out[8]  = fmaf(qd, k2.x, out[8]);  out[9]  = fmaf(qd, k2.y, out[9]);
        out[10] = fmaf(qd, k2.z, out[10]); out[11] = fmaf(qd, k2.w, out[11]);
        out[12] = fmaf(qd, k3.x, out[12]); out[13] = fmaf(qd, k3.y, out[13]);
        out[14] = fmaf(qd, k3.z, out[14]); out[15] = fmaf(qd, k3.w, out[15]);
    }

    const float inv = 1.f / (nrm + 1e-6f);
    const size_t gbase = ((size_t)b * SEQ + s0 + r) * DMODEL + h * HDIM + e0;
#pragma unroll
    for (int qd4 = 0; qd4 < 4; ++qd4) {
        float4 o;
        o.x = out[qd4*4+0] * inv; o.y = out[qd4*4+1] * inv;
        o.z = out[qd4*4+2] * inv; o.w = out[qd4*4+3] * inv;
        *(float4*)&q[gbase + qd4 * 4] = o;
    }
}

// ---------------------------------------------------------------------------
extern "C" void kernel_launch(void* const* d_in, const int* in_sizes, int n_in,
                              void* d_out, int out_size, void* d_ws, size_t ws_size,
                              hipStream_t stream)
{
    const float* x  = (const float*)d_in[0];
    const float* Wq = (const float*)d_in[1];
    const float* bq = (const float*)d_in[2];
    const float* Wk = (const float*)d_in[3];
    const float* bk = (const float*)d_in[4];
    const float* Wv = (const float*)d_in[5];
    const float* bv = (const float*)d_in[6];
    const float* Wo = (const float*)d_in[7];
    const float* bo = (const float*)d_in[8];
    float* out = (float*)d_out;

    float* ws    = (float*)d_ws;
    float* buf0  = ws;                               // k, then q, then att (in-place)
    float* buf1  = buf0 + (size_t)NROWS * DMODEL;    // v
    float* kv    = buf1 + (size_t)NROWS * DMODEL;    // [NBH][64][64]
    float* ksum  = kv   + (size_t)NBH * HDIM * HDIM; // [NBH][64]
    float* kvp   = ksum + (size_t)NBH * HDIM;        // [SCHUNK][NBH][64][64]
    float* ksp   = kvp  + (size_t)SCHUNK * NBH * HDIM * HDIM; // [SCHUNK][NBH][64]

    const dim3 gg(NROWS / 128, DMODEL / 128);

    // k = elu(x @ Wk^T + bk) + 1
    gemm_nt<1><<<gg, 256, 0, stream>>>(x, Wk, bk, buf0);
    // v = x @ Wv^T + bv
    gemm_nt<0><<<gg, 256, 0, stream>>>(x, Wv, bv, buf1);
    // kv, ksum (deterministic split-K + reduce)
    kv_partial<<<dim3(NBH, SCHUNK), 256, 0, stream>>>(buf0, buf1, kvp, ksp);
    kv_reduce<<<(NBH * HDIM * HDIM) / 256, 256, 0, stream>>>(kvp, ksp, kv, ksum);
    // q = elu(x @ Wq^T + bq) + 1   (overwrites k)
    gemm_nt<1><<<gg, 256, 0, stream>>>(x, Wq, bq, buf0);
    // att = (q @ kv) / (q @ ksum + 1e-6), in-place over q
    qkv_norm<<<dim3(SEQ / 64, NBATCH, NHEAD), 256, 0, stream>>>(buf0, kv, ksum);
    // out = att @ Wo^T + bo
    gemm_nt<0><<<gg, 256, 0, stream>>>(buf0, Wo, bo, out);
}

// Round 2
// 779.591 us; speedup vs baseline: 2.8215x; 2.8215x over previous
//
#include <hip/hip_runtime.h>
#include <math.h>

#define NROWS  16384   // B*S
#define DMODEL 1024
#define NHEAD  16
#define HDIM   64
#define SEQ    4096
#define NBATCH 4
#define NBH    64      // NBATCH*NHEAD
#define SCHUNK 8       // split-K chunks over S for kv aggregation
#define M1     1048576u

typedef __attribute__((ext_vector_type(8))) short bf16x8;
typedef __attribute__((ext_vector_type(4))) float f32x4;

__device__ __forceinline__ unsigned short f2bf(float f) {
    unsigned u = __float_as_uint(f);
    u += 0x7FFFu + ((u >> 16) & 1u);   // round-to-nearest-even
    return (unsigned short)(u >> 16);
}
__device__ __forceinline__ float bf2f(unsigned short h) {
    return __uint_as_float((unsigned)h << 16);
}

__device__ __forceinline__ void gload16(const void* g, void* l) {
    __builtin_amdgcn_global_load_lds(
        (const __attribute__((address_space(1))) unsigned int*)g,
        (__attribute__((address_space(3))) unsigned int*)l, 16, 0, 0);
}

// ---------------------------------------------------------------------------
// split fp32 -> bf16 hi/lo pair (grid-stride, float4/ushort4 vectorized)
// ---------------------------------------------------------------------------
__global__ __launch_bounds__(256)
void split_pair(const float* __restrict__ a, unsigned short* __restrict__ hi,
                unsigned short* __restrict__ lo, int n4)
{
    int i = blockIdx.x * 256 + threadIdx.x;
    const int stride = gridDim.x * 256;
    for (; i < n4; i += stride) {
        const float4 v = ((const float4*)a)[i];
        ushort4 H, L;
        H.x = f2bf(v.x); L.x = f2bf(v.x - bf2f(H.x));
        H.y = f2bf(v.y); L.y = f2bf(v.y - bf2f(H.y));
        H.z = f2bf(v.z); L.z = f2bf(v.z - bf2f(H.z));
        H.w = f2bf(v.w); L.w = f2bf(v.w - bf2f(H.w));
        ((ushort4*)hi)[i] = H;
        ((ushort4*)lo)[i] = L;
    }
}

// all 4 weight matrices in one launch: dst = [Wq_h,Wq_l,Wk_h,Wk_l,Wv_h,Wv_l,Wo_h,Wo_l]
__global__ __launch_bounds__(256)
void split_w4(const float* __restrict__ a0, const float* __restrict__ a1,
              const float* __restrict__ a2, const float* __restrict__ a3,
              unsigned short* __restrict__ dst)
{
    const int y = blockIdx.y;
    const float* src = (y == 0) ? a0 : (y == 1) ? a1 : (y == 2) ? a2 : a3;
    unsigned short* hi = dst + (size_t)y * 2u * M1;
    unsigned short* lo = hi + M1;
    const int i = blockIdx.x * 256 + threadIdx.x;   // 0..262143 (= 1M/4)
    const float4 v = ((const float4*)src)[i];
    ushort4 H, L;
    H.x = f2bf(v.x); L.x = f2bf(v.x - bf2f(H.x));
    H.y = f2bf(v.y); L.y = f2bf(v.y - bf2f(H.y));
    H.z = f2bf(v.z); L.z = f2bf(v.z - bf2f(H.z));
    H.w = f2bf(v.w); L.w = f2bf(v.w - bf2f(H.w));
    ((ushort4*)hi)[i] = H;
    ((ushort4*)lo)[i] = L;
}

// ---------------------------------------------------------------------------
// Split-bf16 GEMM (NT): C[m,n] = sum_k A[m,k]*W[n,k] + bias[n], optional elu+1.
// A given as bf16 hi/lo [NROWS][1024], W as bf16 hi/lo [1024][1024].
// 128x128 tile, BK=32, 4 waves, 4x4 16x16x32 MFMA frags/wave, 3 passes
// (hi*hi + hi*lo + lo*hi) for near-fp32 accuracy. global_load_lds staging.
// ---------------------------------------------------------------------------
template<int ELU>
__global__ __launch_bounds__(256)
void gemm_split(const unsigned short* __restrict__ Ah, const unsigned short* __restrict__ Al,
                const unsigned short* __restrict__ Wh, const unsigned short* __restrict__ Wl,
                const float* __restrict__ bias, float* __restrict__ C)
{
    __shared__ unsigned short lds[4 * 4096];   // 4 tiles x [128][32] bf16 = 32 KB
    const int t    = threadIdx.x;
    const int lane = t & 63;
    const int w    = t >> 6;        // wave 0..3 -> (wr,wc) 2x2 of 64x64
    const int wr   = w >> 1;
    const int wc   = w & 1;
    const int m0   = blockIdx.x * 128;
    const int n0   = blockIdx.y * 128;
    const int srow = lane >> 2;         // staging: row-within-16
    const int scol = (lane & 3) * 8;    // staging: k offset (8 bf16 = 16B)
    const int fr   = lane & 15;         // frag row/col
    const int kq   = (lane >> 4) * 8;   // frag k offset (contiguous 8)

    f32x4 acc[4][4];
#pragma unroll
    for (int i = 0; i < 4; ++i)
#pragma unroll
        for (int j = 0; j < 4; ++j)
#pragma unroll
            for (int e = 0; e < 4; ++e) acc[i][j][e] = 0.f;

    for (int k0 = 0; k0 < DMODEL; k0 += 32) {
        // stage 4 tiles: per wave, 2 chunks of 16 rows x 64B each
#pragma unroll
        for (int c = 0; c < 2; ++c) {
            const int rr = (c * 4 + w) * 16 + srow;
            const size_t goffA = (size_t)(m0 + rr) * DMODEL + k0 + scol;
            const size_t goffB = (size_t)(n0 + rr) * DMODEL + k0 + scol;
            unsigned short* lbase = (unsigned short*)lds + (c * 4 + w) * 512;  // wave-uniform
            gload16(Ah + goffA, lbase);
            gload16(Al + goffA, lbase + 4096);
            gload16(Wh + goffB, lbase + 8192);
            gload16(Wl + goffB, lbase + 12288);
        }
        __syncthreads();   // drains vmcnt(0): tiles visible

        bf16x8 ah[4], al[4], bh[4], bl[4];
#pragma unroll
        for (int i = 0; i < 4; ++i) {
            const int ar = wr * 64 + i * 16 + fr;
            const int br = wc * 64 + i * 16 + fr;
            ah[i] = *(const bf16x8*)&lds[ar * 32 + kq];
            al[i] = *(const bf16x8*)&lds[4096 + ar * 32 + kq];
            bh[i] = *(const bf16x8*)&lds[8192 + br * 32 + kq];
            bl[i] = *(const bf16x8*)&lds[12288 + br * 32 + kq];
        }
#pragma unroll
        for (int i = 0; i < 4; ++i)
#pragma unroll
            for (int j = 0; j < 4; ++j) {
                acc[i][j] = __builtin_amdgcn_mfma_f32_16x16x32_bf16(ah[i], bh[j], acc[i][j], 0, 0, 0);
                acc[i][j] = __builtin_amdgcn_mfma_f32_16x16x32_bf16(ah[i], bl[j], acc[i][j], 0, 0, 0);
                acc[i][j] = __builtin_amdgcn_mfma_f32_16x16x32_bf16(al[i], bh[j], acc[i][j], 0, 0, 0);
            }
        __syncthreads();   // all reads done before next stage overwrites
    }

    // epilogue: C/D layout col=lane&15, row=(lane>>4)*4+reg  (m89/m91-verified)
    const int crow0 = m0 + wr * 64 + (lane >> 4) * 4;
    const int ccol0 = n0 + wc * 64 + fr;
#pragma unroll
    for (int j = 0; j < 4; ++j) {
        const int col = ccol0 + j * 16;
        const float bv = bias[col];
#pragma unroll
        for (int i = 0; i < 4; ++i) {
            const int row = crow0 + i * 16;
#pragma unroll
            for (int r = 0; r < 4; ++r) {
                float v = acc[i][j][r] + bv;
                if (ELU) v = (v > 0.f) ? (v + 1.f) : __expf(v);  // elu(v)+1
                C[(size_t)(row + r) * DMODEL + col] = v;
            }
        }
    }
}

// ---------------------------------------------------------------------------
// kv partials: for (b,h,schunk): kvp[d][e] = sum_{s in chunk} k[s,d]*v[s,e],
// ksp[d] = sum k[s,d]. Deterministic split-K (no atomics).
// ---------------------------------------------------------------------------
__global__ __launch_bounds__(256)
void kv_partial(const float* __restrict__ k, const float* __restrict__ v,
                float* __restrict__ kvp, float* __restrict__ ksp)
{
    __shared__ float Ks[32][64];
    __shared__ float Vs[32][64];
    const int t  = threadIdx.x;
    const int bh = blockIdx.x;
    const int b  = bh >> 4;
    const int h  = bh & 15;
    const int sc = blockIdx.y;
    const int d  = t & 63;
    const int e0 = (t >> 6) * 16;

    float acc[16];
#pragma unroll
    for (int j = 0; j < 16; ++j) acc[j] = 0.f;
    float ks = 0.f;

    const size_t rowbase = (size_t)b * SEQ;
    const int sbeg = sc * (SEQ / SCHUNK);
    const int send = sbeg + (SEQ / SCHUNK);

    for (int s0 = sbeg; s0 < send; s0 += 32) {
#pragma unroll
        for (int i = 0; i < 2; ++i) {
            const int idx = i * 256 + t;
            const int row = idx >> 4;
            const int c4  = (idx & 15) * 4;
            const size_t g = (rowbase + s0 + row) * DMODEL + h * HDIM + c4;
            *(float4*)&Ks[row][c4] = *(const float4*)&k[g];
            *(float4*)&Vs[row][c4] = *(const float4*)&v[g];
        }
        __syncthreads();
#pragma unroll
        for (int sp = 0; sp < 32; ++sp) {
            const float kd = Ks[sp][d];
            if (t < 64) ks += Ks[sp][t];
            const float4 v0 = *(const float4*)&Vs[sp][e0 + 0];
            const float4 v1 = *(const float4*)&Vs[sp][e0 + 4];
            const float4 v2 = *(const float4*)&Vs[sp][e0 + 8];
            const float4 v3 = *(const float4*)&Vs[sp][e0 + 12];
            acc[0]  = fmaf(kd, v0.x, acc[0]);  acc[1]  = fmaf(kd, v0.y, acc[1]);
            acc[2]  = fmaf(kd, v0.z, acc[2]);  acc[3]  = fmaf(kd, v0.w, acc[3]);
            acc[4]  = fmaf(kd, v1.x, acc[4]);  acc[5]  = fmaf(kd, v1.y, acc[5]);
            acc[6]  = fmaf(kd, v1.z, acc[6]);  acc[7]  = fmaf(kd, v1.w, acc[7]);
            acc[8]  = fmaf(kd, v2.x, acc[8]);  acc[9]  = fmaf(kd, v2.y, acc[9]);
            acc[10] = fmaf(kd, v2.z, acc[10]); acc[11] = fmaf(kd, v2.w, acc[11]);
            acc[12] = fmaf(kd, v3.x, acc[12]); acc[13] = fmaf(kd, v3.y, acc[13]);
            acc[14] = fmaf(kd, v3.z, acc[14]); acc[15] = fmaf(kd, v3.w, acc[15]);
        }
        __syncthreads();
    }

    const size_t base = ((size_t)sc * NBH + bh) * HDIM;
#pragma unroll
    for (int q = 0; q < 4; ++q) {
        float4 o; o.x = acc[q*4+0]; o.y = acc[q*4+1]; o.z = acc[q*4+2]; o.w = acc[q*4+3];
        *(float4*)&kvp[(base + d) * HDIM + e0 + q * 4] = o;
    }
    if (t < 64) ksp[base + t] = ks;
}

__global__ __launch_bounds__(256)
void kv_reduce(const float* __restrict__ kvp, const float* __restrict__ ksp,
               float* __restrict__ kv, float* __restrict__ ksum)
{
    const int i = blockIdx.x * 256 + threadIdx.x;
    const int NKV = NBH * HDIM * HDIM;
    if (i < NKV) {
        float s = 0.f;
#pragma unroll
        for (int c = 0; c < SCHUNK; ++c) s += kvp[(size_t)c * NKV + i];
        kv[i] = s;
    }
    if (i < NBH * HDIM) {
        float s = 0.f;
#pragma unroll
        for (int c = 0; c < SCHUNK; ++c) s += ksp[(size_t)c * NBH * HDIM + i];
        ksum[i] = s;
    }
}

// ---------------------------------------------------------------------------
// att[s,e] = (sum_d q[s,d]*kv[d,e]) / (sum_d q[s,d]*ksum[d] + 1e-6), in-place.
// ---------------------------------------------------------------------------
__global__ __launch_bounds__(256)
void qkv_norm(float* __restrict__ q, const float* __restrict__ kv,
              const float* __restrict__ ksum)
{
    __shared__ float Qs[64][68];
    __shared__ float KVs[64][64];
    __shared__ float kss[64];
    const int t  = threadIdx.x;
    const int s0 = blockIdx.x * 64;
    const int b  = blockIdx.y;
    const int h  = blockIdx.z;
    const int bh = b * NHEAD + h;

#pragma unroll
    for (int i = 0; i < 4; ++i) {
        const int idx = i * 256 + t;
        const int row = idx >> 4;
        const int c4  = (idx & 15) * 4;
        const float4 vq = *(const float4*)&q[((size_t)b * SEQ + s0 + row) * DMODEL + h * HDIM + c4];
        *(float4*)&Qs[row][c4] = vq;
        *(float4*)&((float*)KVs)[idx * 4] = *(const float4*)&kv[(size_t)bh * HDIM * HDIM + idx * 4];
    }
    if (t < 64) kss[t] = ksum[(size_t)bh * HDIM + t];
    __syncthreads();

    const int r  = t >> 2;
    const int e0 = (t & 3) * 16;
    float out[16];
#pragma unroll
    for (int j = 0; j < 16; ++j) out[j] = 0.f;
    float nrm = 0.f;

#pragma unroll 8
    for (int d = 0; d < 64; ++d) {
        const float qd = Qs[r][d];
        nrm = fmaf(qd, kss[d], nrm);
        const float4 k0 = *(const float4*)&KVs[d][e0 + 0];
        const float4 k1 = *(const float4*)&KVs[d][e0 + 4];
        const float4 k2 = *(const float4*)&KVs[d][e0 + 8];
        const float4 k3 = *(const float4*)&KVs[d][e0 + 12];
        out[0]  = fmaf(qd, k0.x, out[0]);  out[1]  = fmaf(qd, k0.y, out[1]);
        out[2]  = fmaf(qd, k0.z, out[2]);  out[3]  = fmaf(qd, k0.w, out[3]);
        out[4]  = fmaf(qd, k1.x, out[4]);  out[5]  = fmaf(qd, k1.y, out[5]);
        out[6]  = fmaf(qd, k1.z, out[6]);  out[7]  = fmaf(qd, k1.w, out[7]);
        out[8]  = fmaf(qd, k2.x, out[8]);  out[9]  = fmaf(qd, k2.y, out[9]);
        out[10] = fmaf(qd, k2.z, out[10]); out[11] = fmaf(qd, k2.w, out[11]);
        out[12] = fmaf(qd, k3.x, out[12]); out[13] = fmaf(qd, k3.y, out[13]);
        out[14] = fmaf(qd, k3.z, out[14]); out[15] = fmaf(qd, k3.w, out[15]);
    }

    const float inv = 1.f / (nrm + 1e-6f);
    const size_t gbase = ((size_t)b * SEQ + s0 + r) * DMODEL + h * HDIM + e0;
#pragma unroll
    for (int qd4 = 0; qd4 < 4; ++qd4) {
        float4 o;
        o.x = out[qd4*4+0] * inv; o.y = out[qd4*4+1] * inv;
        o.z = out[qd4*4+2] * inv; o.w = out[qd4*4+3] * inv;
        *(float4*)&q[gbase + qd4 * 4] = o;
    }
}

// ---------------------------------------------------------------------------
extern "C" void kernel_launch(void* const* d_in, const int* in_sizes, int n_in,
                              void* d_out, int out_size, void* d_ws, size_t ws_size,
                              hipStream_t stream)
{
    const float* x  = (const float*)d_in[0];
    const float* Wq = (const float*)d_in[1];
    const float* bq = (const float*)d_in[2];
    const float* Wk = (const float*)d_in[3];
    const float* bk = (const float*)d_in[4];
    const float* Wv = (const float*)d_in[5];
    const float* bv = (const float*)d_in[6];
    const float* Wo = (const float*)d_in[7];
    const float* bo = (const float*)d_in[8];

    // workspace layout (~153 MB):
    unsigned short* xh = (unsigned short*)d_ws;                    // [16384][1024] bf16 hi
    unsigned short* xl = xh + (size_t)NROWS * DMODEL;              // lo
    unsigned short* wsp = xl + (size_t)NROWS * DMODEL;             // 8 x 1M bf16: q_h,q_l,k_h,k_l,v_h,v_l,o_h,o_l
    float* buf0 = (float*)(wsp + 8u * M1);                         // k -> q -> att (fp32, in-place)
    float* kv   = buf0 + (size_t)NROWS * DMODEL;                   // [NBH][64][64]
    float* ksum = kv + NBH * HDIM * HDIM;                          // [NBH][64]
    float* kvp  = ksum + NBH * HDIM;                               // [SCHUNK][NBH][64][64]
    float* ksp  = kvp + (size_t)SCHUNK * NBH * HDIM * HDIM;        // [SCHUNK][NBH][64]
    float* vbuf = (float*)d_out;                                   // v lives in d_out (dead before final GEMM)

    const dim3 gg(NROWS / 128, DMODEL / 128);
    const int n4x = NROWS * DMODEL / 4;

    // convert weights + x to bf16 hi/lo
    split_w4<<<dim3(1024, 4), 256, 0, stream>>>(Wq, Wk, Wv, Wo, wsp);
    split_pair<<<4096, 256, 0, stream>>>(x, xh, xl, n4x);
    // k = elu(x@Wk^T + bk)+1 ; v = x@Wv^T + bv
    gemm_split<1><<<gg, 256, 0, stream>>>(xh, xl, wsp + 2u * M1, wsp + 3u * M1, bk, buf0);
    gemm_split<0><<<gg, 256, 0, stream>>>(xh, xl, wsp + 4u * M1, wsp + 5u * M1, bv, vbuf);
    // kv, ksum
    kv_partial<<<dim3(NBH, SCHUNK), 256, 0, stream>>>(buf0, vbuf, kvp, ksp);
    kv_reduce<<<1024, 256, 0, stream>>>(kvp, ksp, kv, ksum);
    // q = elu(x@Wq^T + bq)+1   (overwrites k)
    gemm_split<1><<<gg, 256, 0, stream>>>(xh, xl, wsp, wsp + M1, bq, buf0);
    // att = (q@kv)/(q@ksum + 1e-6), in-place
    qkv_norm<<<dim3(SEQ / 64, NBATCH, NHEAD), 256, 0, stream>>>(buf0, kv, ksum);
    // att -> bf16 hi/lo (x is dead; reuse xh/xl)
    split_pair<<<4096, 256, 0, stream>>>(buf0, xh, xl, n4x);
    // out = att@Wo^T + bo  (overwrites v in d_out)
    gemm_split<0><<<gg, 256, 0, stream>>>(xh, xl, wsp + 6u * M1, wsp + 7u * M1, bo, (float*)d_out);
}

// Round 3
// 582.069 us; speedup vs baseline: 3.7789x; 1.3393x over previous
//
#include <hip/hip_runtime.h>
#include <math.h>

#define NROWS  16384   // B*S
#define DMODEL 1024
#define NHEAD  16
#define HDIM   64
#define SEQ    4096
#define NBATCH 4
#define NBH    64      // NBATCH*NHEAD
#define SCHUNK 16      // split-K chunks over S for kv aggregation
#define M1     1048576u

typedef __attribute__((ext_vector_type(8))) short bf16x8;
typedef __attribute__((ext_vector_type(4))) float f32x4;

__device__ __forceinline__ unsigned short f2bf(float f) {
    unsigned u = __float_as_uint(f);
    u += 0x7FFFu + ((u >> 16) & 1u);   // round-to-nearest-even
    return (unsigned short)(u >> 16);
}
__device__ __forceinline__ float bf2f(unsigned short h) {
    return __uint_as_float((unsigned)h << 16);
}

__device__ __forceinline__ void gload16(const void* g, void* l) {
    __builtin_amdgcn_global_load_lds(
        (const __attribute__((address_space(1))) unsigned int*)g,
        (__attribute__((address_space(3))) unsigned int*)l, 16, 0, 0);
}

// ---------------------------------------------------------------------------
// split fp32 -> bf16 hi/lo pair (grid-stride, float4/ushort4 vectorized)
// ---------------------------------------------------------------------------
__global__ __launch_bounds__(256)
void split_pair(const float* __restrict__ a, unsigned short* __restrict__ hi,
                unsigned short* __restrict__ lo, int n4)
{
    int i = blockIdx.x * 256 + threadIdx.x;
    const int stride = gridDim.x * 256;
    for (; i < n4; i += stride) {
        const float4 v = ((const float4*)a)[i];
        ushort4 H, L;
        H.x = f2bf(v.x); L.x = f2bf(v.x - bf2f(H.x));
        H.y = f2bf(v.y); L.y = f2bf(v.y - bf2f(H.y));
        H.z = f2bf(v.z); L.z = f2bf(v.z - bf2f(H.z));
        H.w = f2bf(v.w); L.w = f2bf(v.w - bf2f(H.w));
        ((ushort4*)hi)[i] = H;
        ((ushort4*)lo)[i] = L;
    }
}

// all 4 weight matrices in one launch: dst = [Wq_h,Wq_l,Wk_h,Wk_l,Wv_h,Wv_l,Wo_h,Wo_l]
__global__ __launch_bounds__(256)
void split_w4(const float* __restrict__ a0, const float* __restrict__ a1,
              const float* __restrict__ a2, const float* __restrict__ a3,
              unsigned short* __restrict__ dst)
{
    const int y = blockIdx.y;
    const float* src = (y == 0) ? a0 : (y == 1) ? a1 : (y == 2) ? a2 : a3;
    unsigned short* hi = dst + (size_t)y * 2u * M1;
    unsigned short* lo = hi + M1;
    const int i = blockIdx.x * 256 + threadIdx.x;   // 0..262143 (= 1M/4)
    const float4 v = ((const float4*)src)[i];
    ushort4 H, L;
    H.x = f2bf(v.x); L.x = f2bf(v.x - bf2f(H.x));
    H.y = f2bf(v.y); L.y = f2bf(v.y - bf2f(H.y));
    H.z = f2bf(v.z); L.z = f2bf(v.z - bf2f(H.z));
    H.w = f2bf(v.w); L.w = f2bf(v.w - bf2f(H.w));
    ((ushort4*)hi)[i] = H;
    ((ushort4*)lo)[i] = L;
}

// ---------------------------------------------------------------------------
// Split-bf16 GEMM (NT): C[m,n] = sum_k A[m,k]*W[n,k] + bias[n], optional elu+1.
// 128x128 tile, BK=32, 4 waves, 4x4 16x16x32 MFMA frags/wave, 3 passes
// (hi*hi + hi*lo + lo*hi) for near-fp32 accuracy. global_load_lds staging.
// ---------------------------------------------------------------------------
template<int ELU>
__global__ __launch_bounds__(256)
void gemm_split(const unsigned short* __restrict__ Ah, const unsigned short* __restrict__ Al,
                const unsigned short* __restrict__ Wh, const unsigned short* __restrict__ Wl,
                const float* __restrict__ bias, float* __restrict__ C)
{
    __shared__ unsigned short lds[4 * 4096];   // 4 tiles x [128][32] bf16 = 32 KB
    const int t    = threadIdx.x;
    const int lane = t & 63;
    const int w    = t >> 6;        // wave 0..3 -> (wr,wc) 2x2 of 64x64
    const int wr   = w >> 1;
    const int wc   = w & 1;
    const int m0   = blockIdx.x * 128;
    const int n0   = blockIdx.y * 128;
    const int srow = lane >> 2;         // staging: row-within-16
    const int scol = (lane & 3) * 8;    // staging: k offset (8 bf16 = 16B)
    const int fr   = lane & 15;         // frag row/col
    const int kq   = (lane >> 4) * 8;   // frag k offset (contiguous 8)

    f32x4 acc[4][4];
#pragma unroll
    for (int i = 0; i < 4; ++i)
#pragma unroll
        for (int j = 0; j < 4; ++j)
#pragma unroll
            for (int e = 0; e < 4; ++e) acc[i][j][e] = 0.f;

    for (int k0 = 0; k0 < DMODEL; k0 += 32) {
        // stage 4 tiles: per wave, 2 chunks of 16 rows x 64B each
#pragma unroll
        for (int c = 0; c < 2; ++c) {
            const int rr = (c * 4 + w) * 16 + srow;
            const size_t goffA = (size_t)(m0 + rr) * DMODEL + k0 + scol;
            const size_t goffB = (size_t)(n0 + rr) * DMODEL + k0 + scol;
            unsigned short* lbase = (unsigned short*)lds + (c * 4 + w) * 512;  // wave-uniform
            gload16(Ah + goffA, lbase);
            gload16(Al + goffA, lbase + 4096);
            gload16(Wh + goffB, lbase + 8192);
            gload16(Wl + goffB, lbase + 12288);
        }
        __syncthreads();   // drains vmcnt(0): tiles visible

        bf16x8 ah[4], al[4], bh[4], bl[4];
#pragma unroll
        for (int i = 0; i < 4; ++i) {
            const int ar = wr * 64 + i * 16 + fr;
            const int br = wc * 64 + i * 16 + fr;
            ah[i] = *(const bf16x8*)&lds[ar * 32 + kq];
            al[i] = *(const bf16x8*)&lds[4096 + ar * 32 + kq];
            bh[i] = *(const bf16x8*)&lds[8192 + br * 32 + kq];
            bl[i] = *(const bf16x8*)&lds[12288 + br * 32 + kq];
        }
#pragma unroll
        for (int i = 0; i < 4; ++i)
#pragma unroll
            for (int j = 0; j < 4; ++j) {
                acc[i][j] = __builtin_amdgcn_mfma_f32_16x16x32_bf16(ah[i], bh[j], acc[i][j], 0, 0, 0);
                acc[i][j] = __builtin_amdgcn_mfma_f32_16x16x32_bf16(ah[i], bl[j], acc[i][j], 0, 0, 0);
                acc[i][j] = __builtin_amdgcn_mfma_f32_16x16x32_bf16(al[i], bh[j], acc[i][j], 0, 0, 0);
            }
        __syncthreads();   // all reads done before next stage overwrites
    }

    // epilogue: C/D layout col=lane&15, row=(lane>>4)*4+reg  (m89/m91-verified)
    const int crow0 = m0 + wr * 64 + (lane >> 4) * 4;
    const int ccol0 = n0 + wc * 64 + fr;
#pragma unroll
    for (int j = 0; j < 4; ++j) {
        const int col = ccol0 + j * 16;
        const float bv = bias[col];
#pragma unroll
        for (int i = 0; i < 4; ++i) {
            const int row = crow0 + i * 16;
#pragma unroll
            for (int r = 0; r < 4; ++r) {
                float v = acc[i][j][r] + bv;
                if (ELU) v = (v > 0.f) ? (v + 1.f) : __expf(v);  // elu(v)+1
                C[(size_t)(row + r) * DMODEL + col] = v;
            }
        }
    }
}

// ---------------------------------------------------------------------------
// kv partials: for (b,h,sc): kvp[d][e] = sum_{s in chunk} k[s,d]*v[s,e],
// ksp[d] = sum k[s,d]. Deterministic split-K, no atomics.
// grid (NBH, SCHUNK), 512 threads. thread: d=t&63, e-range=(t>>6)*8..+7.
// 256 rows per block in stages of 32. acc[8] keeps VGPR low for occupancy.
// ---------------------------------------------------------------------------
__global__ __launch_bounds__(512)
void kv_partial(const float* __restrict__ k, const float* __restrict__ v,
                float* __restrict__ kvp, float* __restrict__ ksp)
{
    __shared__ float Ks[32][64];
    __shared__ float Vs[32][64];
    const int t  = threadIdx.x;
    const int bh = blockIdx.x;
    const int b  = bh >> 4;
    const int h  = bh & 15;
    const int sc = blockIdx.y;
    const int d  = t & 63;
    const int e0 = (t >> 6) * 8;

    float acc[8];
#pragma unroll
    for (int j = 0; j < 8; ++j) acc[j] = 0.f;
    float ks = 0.f;

    const size_t rowbase = (size_t)b * SEQ;
    const int sbeg = sc * (SEQ / SCHUNK);       // 256 rows per chunk
    const int send = sbeg + (SEQ / SCHUNK);
    const int lrow = t >> 4;                    // staging: 0..31
    const int lc4  = (t & 15) * 4;

    for (int s0 = sbeg; s0 < send; s0 += 32) {
        const size_t g = (rowbase + s0 + lrow) * DMODEL + h * HDIM + lc4;
        *(float4*)&Ks[lrow][lc4] = *(const float4*)&k[g];
        *(float4*)&Vs[lrow][lc4] = *(const float4*)&v[g];
        __syncthreads();
#pragma unroll 8
        for (int sp = 0; sp < 32; ++sp) {
            const float kd = Ks[sp][d];
            if (t < 64) ks += Ks[sp][t];        // wave 0 only (wave-uniform branch)
            const float4 v0 = *(const float4*)&Vs[sp][e0 + 0];
            const float4 v1 = *(const float4*)&Vs[sp][e0 + 4];
            acc[0] = fmaf(kd, v0.x, acc[0]);  acc[1] = fmaf(kd, v0.y, acc[1]);
            acc[2] = fmaf(kd, v0.z, acc[2]);  acc[3] = fmaf(kd, v0.w, acc[3]);
            acc[4] = fmaf(kd, v1.x, acc[4]);  acc[5] = fmaf(kd, v1.y, acc[5]);
            acc[6] = fmaf(kd, v1.z, acc[6]);  acc[7] = fmaf(kd, v1.w, acc[7]);
        }
        __syncthreads();
    }

    const size_t base = ((size_t)sc * NBH + bh) * HDIM;
    float4 o0; o0.x = acc[0]; o0.y = acc[1]; o0.z = acc[2]; o0.w = acc[3];
    float4 o1; o1.x = acc[4]; o1.y = acc[5]; o1.z = acc[6]; o1.w = acc[7];
    *(float4*)&kvp[(base + d) * HDIM + e0 + 0] = o0;
    *(float4*)&kvp[(base + d) * HDIM + e0 + 4] = o1;
    if (t < 64) ksp[base + t] = ks;
}

__global__ __launch_bounds__(256)
void kv_reduce(const float* __restrict__ kvp, const float* __restrict__ ksp,
               float* __restrict__ kv, float* __restrict__ ksum)
{
    const int i = blockIdx.x * 256 + threadIdx.x;
    const int NKV = NBH * HDIM * HDIM;
    if (i < NKV) {
        float s = 0.f;
#pragma unroll
        for (int c = 0; c < SCHUNK; ++c) s += kvp[(size_t)c * NKV + i];
        kv[i] = s;
    }
    if (i < NBH * HDIM) {
        float s = 0.f;
#pragma unroll
        for (int c = 0; c < SCHUNK; ++c) s += ksp[(size_t)c * NBH * HDIM + i];
        ksum[i] = s;
    }
}

// ---------------------------------------------------------------------------
// att[s,e] = (sum_d q[s,d]*kv[d,e]) / (sum_d q[s,d]*ksum[d] + 1e-6),
// written directly as bf16 hi/lo (fused split for the final GEMM's A-operand).
// ---------------------------------------------------------------------------
__global__ __launch_bounds__(256)
void qkv_norm(const float* __restrict__ q, const float* __restrict__ kv,
              const float* __restrict__ ksum,
              unsigned short* __restrict__ ah, unsigned short* __restrict__ al)
{
    __shared__ float Qs[64][68];
    __shared__ float KVs[64][64];
    __shared__ float kss[64];
    const int t  = threadIdx.x;
    const int s0 = blockIdx.x * 64;
    const int b  = blockIdx.y;
    const int h  = blockIdx.z;
    const int bh = b * NHEAD + h;

#pragma unroll
    for (int i = 0; i < 4; ++i) {
        const int idx = i * 256 + t;
        const int row = idx >> 4;
        const int c4  = (idx & 15) * 4;
        const float4 vq = *(const float4*)&q[((size_t)b * SEQ + s0 + row) * DMODEL + h * HDIM + c4];
        *(float4*)&Qs[row][c4] = vq;
        *(float4*)&((float*)KVs)[idx * 4] = *(const float4*)&kv[(size_t)bh * HDIM * HDIM + idx * 4];
    }
    if (t < 64) kss[t] = ksum[(size_t)bh * HDIM + t];
    __syncthreads();

    const int r  = t >> 2;
    const int e0 = (t & 3) * 16;
    float out[16];
#pragma unroll
    for (int j = 0; j < 16; ++j) out[j] = 0.f;
    float nrm = 0.f;

#pragma unroll 8
    for (int d = 0; d < 64; ++d) {
        const float qd = Qs[r][d];
        nrm = fmaf(qd, kss[d], nrm);
        const float4 k0 = *(const float4*)&KVs[d][e0 + 0];
        const float4 k1 = *(const float4*)&KVs[d][e0 + 4];
        const float4 k2 = *(const float4*)&KVs[d][e0 + 8];
        const float4 k3 = *(const float4*)&KVs[d][e0 + 12];
        out[0]  = fmaf(qd, k0.x, out[0]);  out[1]  = fmaf(qd, k0.y, out[1]);
        out[2]  = fmaf(qd, k0.z, out[2]);  out[3]  = fmaf(qd, k0.w, out[3]);
        out[4]  = fmaf(qd, k1.x, out[4]);  out[5]  = fmaf(qd, k1.y, out[5]);
        out[6]  = fmaf(qd, k1.z, out[6]);  out[7]  = fmaf(qd, k1.w, out[7]);
        out[8]  = fmaf(qd, k2.x, out[8]);  out[9]  = fmaf(qd, k2.y, out[9]);
        out[10] = fmaf(qd, k2.z, out[10]); out[11] = fmaf(qd, k2.w, out[11]);
        out[12] = fmaf(qd, k3.x, out[12]); out[13] = fmaf(qd, k3.y, out[13]);
        out[14] = fmaf(qd, k3.z, out[14]); out[15] = fmaf(qd, k3.w, out[15]);
    }

    const float inv = 1.f / (nrm + 1e-6f);
    const size_t gbase = ((size_t)b * SEQ + s0 + r) * DMODEL + h * HDIM + e0;
#pragma unroll
    for (int g4 = 0; g4 < 4; ++g4) {
        ushort4 H, L;
        const float v0 = out[g4*4+0] * inv;
        const float v1 = out[g4*4+1] * inv;
        const float v2 = out[g4*4+2] * inv;
        const float v3 = out[g4*4+3] * inv;
        H.x = f2bf(v0); L.x = f2bf(v0 - bf2f(H.x));
        H.y = f2bf(v1); L.y = f2bf(v1 - bf2f(H.y));
        H.z = f2bf(v2); L.z = f2bf(v2 - bf2f(H.z));
        H.w = f2bf(v3); L.w = f2bf(v3 - bf2f(H.w));
        *(ushort4*)&ah[gbase + g4 * 4] = H;
        *(ushort4*)&al[gbase + g4 * 4] = L;
    }
}

// ---------------------------------------------------------------------------
extern "C" void kernel_launch(void* const* d_in, const int* in_sizes, int n_in,
                              void* d_out, int out_size, void* d_ws, size_t ws_size,
                              hipStream_t stream)
{
    const float* x  = (const float*)d_in[0];
    const float* Wq = (const float*)d_in[1];
    const float* bq = (const float*)d_in[2];
    const float* Wk = (const float*)d_in[3];
    const float* bk = (const float*)d_in[4];
    const float* Wv = (const float*)d_in[5];
    const float* bv = (const float*)d_in[6];
    const float* Wo = (const float*)d_in[7];
    const float* bo = (const float*)d_in[8];

    // workspace layout (~163 MB):
    unsigned short* xh = (unsigned short*)d_ws;                    // [16384][1024] bf16 hi (x, then att)
    unsigned short* xl = xh + (size_t)NROWS * DMODEL;              // lo
    unsigned short* wsp = xl + (size_t)NROWS * DMODEL;             // 8 x 1M bf16: q_h,q_l,k_h,k_l,v_h,v_l,o_h,o_l
    float* buf0 = (float*)(wsp + 8u * M1);                         // k, then q (fp32)
    float* kv   = buf0 + (size_t)NROWS * DMODEL;                   // [NBH][64][64]
    float* ksum = kv + NBH * HDIM * HDIM;                          // [NBH][64]
    float* kvp  = ksum + NBH * HDIM;                               // [SCHUNK][NBH][64][64]
    float* ksp  = kvp + (size_t)SCHUNK * NBH * HDIM * HDIM;        // [SCHUNK][NBH][64]
    float* vbuf = (float*)d_out;                                   // v lives in d_out (dead before final GEMM)

    const dim3 gg(NROWS / 128, DMODEL / 128);
    const int n4x = NROWS * DMODEL / 4;

    // convert weights + x to bf16 hi/lo
    split_w4<<<dim3(1024, 4), 256, 0, stream>>>(Wq, Wk, Wv, Wo, wsp);
    split_pair<<<4096, 256, 0, stream>>>(x, xh, xl, n4x);
    // k = elu(x@Wk^T + bk)+1 ; v = x@Wv^T + bv
    gemm_split<1><<<gg, 256, 0, stream>>>(xh, xl, wsp + 2u * M1, wsp + 3u * M1, bk, buf0);
    gemm_split<0><<<gg, 256, 0, stream>>>(xh, xl, wsp + 4u * M1, wsp + 5u * M1, bv, vbuf);
    // kv, ksum (deterministic split-K + reduce)
    kv_partial<<<dim3(NBH, SCHUNK), 512, 0, stream>>>(buf0, vbuf, kvp, ksp);
    kv_reduce<<<1024, 256, 0, stream>>>(kvp, ksp, kv, ksum);
    // q = elu(x@Wq^T + bq)+1   (overwrites k)
    gemm_split<1><<<gg, 256, 0, stream>>>(xh, xl, wsp, wsp + M1, bq, buf0);
    // att = (q@kv)/(q@ksum + 1e-6), fused bf16 hi/lo split (x split is dead; reuse xh/xl)
    qkv_norm<<<dim3(SEQ / 64, NBATCH, NHEAD), 256, 0, stream>>>(buf0, kv, ksum, xh, xl);
    // out = att@Wo^T + bo  (overwrites v in d_out)
    gemm_split<0><<<gg, 256, 0, stream>>>(xh, xl, wsp + 6u * M1, wsp + 7u * M1, bo, (float*)d_out);
}

// Round 4
// 485.481 us; speedup vs baseline: 4.5307x; 1.1990x over previous
//
#include <hip/hip_runtime.h>
#include <math.h>

#define NROWS  16384   // B*S
#define DMODEL 1024
#define NHEAD  16
#define HDIM   64
#define SEQ    4096
#define NBATCH 4
#define NBH    64      // NBATCH*NHEAD
#define SCHUNK 16      // split-K chunks over S for kv aggregation
#define M1     1048576u

typedef __attribute__((ext_vector_type(8))) short bf16x8;
typedef __attribute__((ext_vector_type(4))) float f32x4;

__device__ __forceinline__ unsigned short f2bf(float f) {
    unsigned u = __float_as_uint(f);
    u += 0x7FFFu + ((u >> 16) & 1u);   // round-to-nearest-even
    return (unsigned short)(u >> 16);
}
__device__ __forceinline__ float bf2f(unsigned short h) {
    return __uint_as_float((unsigned)h << 16);
}

__device__ __forceinline__ void gload16(const void* g, void* l) {
    __builtin_amdgcn_global_load_lds(
        (const __attribute__((address_space(1))) unsigned int*)g,
        (__attribute__((address_space(3))) unsigned int*)l, 16, 0, 0);
}

// ---------------------------------------------------------------------------
// split fp32 -> bf16 hi/lo pair (grid-stride, float4/ushort4 vectorized)
// ---------------------------------------------------------------------------
__global__ __launch_bounds__(256)
void split_pair(const float* __restrict__ a, unsigned short* __restrict__ hi,
                unsigned short* __restrict__ lo, int n4)
{
    int i = blockIdx.x * 256 + threadIdx.x;
    const int stride = gridDim.x * 256;
    for (; i < n4; i += stride) {
        const float4 v = ((const float4*)a)[i];
        ushort4 H, L;
        H.x = f2bf(v.x); L.x = f2bf(v.x - bf2f(H.x));
        H.y = f2bf(v.y); L.y = f2bf(v.y - bf2f(H.y));
        H.z = f2bf(v.z); L.z = f2bf(v.z - bf2f(H.z));
        H.w = f2bf(v.w); L.w = f2bf(v.w - bf2f(H.w));
        ((ushort4*)hi)[i] = H;
        ((ushort4*)lo)[i] = L;
    }
}

// all 4 weight matrices in one launch: dst = [Wq_h,Wq_l,Wk_h,Wk_l,Wv_h,Wv_l,Wo_h,Wo_l]
__global__ __launch_bounds__(256)
void split_w4(const float* __restrict__ a0, const float* __restrict__ a1,
              const float* __restrict__ a2, const float* __restrict__ a3,
              unsigned short* __restrict__ dst)
{
    const int y = blockIdx.y;
    const float* src = (y == 0) ? a0 : (y == 1) ? a1 : (y == 2) ? a2 : a3;
    unsigned short* hi = dst + (size_t)y * 2u * M1;
    unsigned short* lo = hi + M1;
    const int i = blockIdx.x * 256 + threadIdx.x;   // 0..262143 (= 1M/4)
    const float4 v = ((const float4*)src)[i];
    ushort4 H, L;
    H.x = f2bf(v.x); L.x = f2bf(v.x - bf2f(H.x));
    H.y = f2bf(v.y); L.y = f2bf(v.y - bf2f(H.y));
    H.z = f2bf(v.z); L.z = f2bf(v.z - bf2f(H.z));
    H.w = f2bf(v.w); L.w = f2bf(v.w - bf2f(H.w));
    ((ushort4*)hi)[i] = H;
    ((ushort4*)lo)[i] = L;
}

// ---------------------------------------------------------------------------
// Split-bf16 GEMM (NT), deep-pipelined: C = A@W^T + bias, optional elu+1.
// 256x256 tile, BK=32, 8 waves (2Mx4N), per-wave 128x64 = 8x4 16x16x32 frags,
// 3 MFMA passes (hh+hl+lh). LDS 2 x {Ah,Al,Bh,Bl}[256][32] = 128 KiB dbuf,
// 1 block/CU, grid 256 = CU count. 4 phases/K-step with raw s_barriers;
// prefetch gload16s stay in flight across the whole step (T3/T4), single
// __syncthreads() (vmcnt0) per step at buffer handoff. T5 setprio on MFMA.
// T1 bijective XCD swizzle (A-panel reuse within XCD L2).
// ---------------------------------------------------------------------------
template<int ELU>
__global__ __launch_bounds__(512)
void gemm_split8(const unsigned short* __restrict__ Ah, const unsigned short* __restrict__ Al,
                 const unsigned short* __restrict__ Wh, const unsigned short* __restrict__ Wl,
                 const float* __restrict__ bias, float* __restrict__ C)
{
    __shared__ unsigned short lds[2 * 32768];   // 2 x 64 KiB buffers
    const int t    = threadIdx.x;
    const int lane = t & 63;
    const int wv   = t >> 6;        // wave 0..7
    const int wr   = wv >> 2;       // M half   0..1
    const int wcn  = wv & 3;        // N quarter 0..3

    // XCD swizzle: XCD x gets contiguous work [x*32, x*32+32) -> 8 m-panels x all n
    const int bid  = blockIdx.x;
    const int swz  = ((bid & 7) << 5) | (bid >> 3);
    const int am0  = (swz >> 2) * 256;     // A panel row base
    const int bn0  = (swz & 3) * 256;      // W panel row base (= C col base)

    const int srow = lane >> 2;            // staging row within 16-row chunk
    const int scol = (lane & 3) * 8;       // staging k-slot (8 bf16 = 16B)
    const int fr   = lane & 15;            // frag row/col
    const int j0   = lane >> 4;            // frag k-slot 0..3

    f32x4 acc[8][4];
#pragma unroll
    for (int i = 0; i < 8; ++i)
#pragma unroll
        for (int j = 0; j < 4; ++j)
#pragma unroll
            for (int e = 0; e < 4; ++e) acc[i][j][e] = 0.f;

    // stage one tile quarter (ph: 0=Ah 1=Al 2=Bh 3=Bl) for k0 into buffer wb
    auto stage = [&](int ph, int k0, unsigned wb) {
        const unsigned short* gs = (ph == 0) ? Ah : (ph == 1) ? Al : (ph == 2) ? Wh : Wl;
        const int rbase = (ph < 2) ? am0 : bn0;
#pragma unroll
        for (int c = 0; c < 2; ++c) {
            const int grow = rbase + c * 128 + wv * 16 + srow;
            gload16(gs + (size_t)grow * DMODEL + k0 + scol,
                    (unsigned short*)&lds[wb + (unsigned)ph * 8192u + (unsigned)(c * 128 + wv * 16) * 32u]);
        }
    };

    // prologue: stage K-step 0 into buffer 0
#pragma unroll
    for (int ph = 0; ph < 4; ++ph) stage(ph, 0, 0u);
    __syncthreads();

    for (int ks = 0; ks < 32; ++ks) {
        const unsigned rb = (ks & 1) ? 32768u : 0u;
        const unsigned wb = rb ^ 32768u;
        const int k0n = (ks + 1) * 32;
        const bool pf = (ks < 31);

        bf16x8 bh[4], bl[4];
#pragma unroll
        for (int ph = 0; ph < 4; ++ph) {
            if (ph == 0) {
#pragma unroll
                for (int j = 0; j < 4; ++j) {
                    const unsigned ro = (unsigned)(wcn * 64 + j * 16 + fr) * 32u + (unsigned)j0 * 8u;
                    bh[j] = *(const bf16x8*)&lds[rb + 16384u + ro];
                    bl[j] = *(const bf16x8*)&lds[rb + 24576u + ro];
                }
            }
            bf16x8 a_h[2], a_l[2];
#pragma unroll
            for (int i2 = 0; i2 < 2; ++i2) {
                const unsigned ro = (unsigned)(wr * 128 + (ph * 2 + i2) * 16 + fr) * 32u + (unsigned)j0 * 8u;
                a_h[i2] = *(const bf16x8*)&lds[rb + ro];
                a_l[i2] = *(const bf16x8*)&lds[rb + 8192u + ro];
            }
            if (pf) stage(ph, k0n, wb);        // prefetch: stays in flight across barriers
            __builtin_amdgcn_s_barrier();
            __builtin_amdgcn_s_setprio(1);
#pragma unroll
            for (int i2 = 0; i2 < 2; ++i2)
#pragma unroll
                for (int j = 0; j < 4; ++j) {
                    acc[ph * 2 + i2][j] = __builtin_amdgcn_mfma_f32_16x16x32_bf16(a_h[i2], bh[j], acc[ph * 2 + i2][j], 0, 0, 0);
                    acc[ph * 2 + i2][j] = __builtin_amdgcn_mfma_f32_16x16x32_bf16(a_h[i2], bl[j], acc[ph * 2 + i2][j], 0, 0, 0);
                    acc[ph * 2 + i2][j] = __builtin_amdgcn_mfma_f32_16x16x32_bf16(a_l[i2], bh[j], acc[ph * 2 + i2][j], 0, 0, 0);
                }
            __builtin_amdgcn_s_setprio(0);
            if (ph < 3) __builtin_amdgcn_s_barrier();
        }
        __syncthreads();   // vmcnt(0)+lgkmcnt(0)+barrier: buffer handoff (once per K-step)
    }

    // epilogue: C/D layout col=lane&15, row=(lane>>4)*4+reg
    const int crow0 = am0 + wr * 128 + (lane >> 4) * 4;
    const int ccol0 = bn0 + wcn * 64 + fr;
#pragma unroll
    for (int j = 0; j < 4; ++j) {
        const int col = ccol0 + j * 16;
        const float bv = bias[col];
#pragma unroll
        for (int i = 0; i < 8; ++i) {
            const int row = crow0 + i * 16;
#pragma unroll
            for (int r = 0; r < 4; ++r) {
                float v = acc[i][j][r] + bv;
                if (ELU) v = (v > 0.f) ? (v + 1.f) : __expf(v);  // elu(v)+1
                C[(size_t)(row + r) * DMODEL + col] = v;
            }
        }
    }
}

// ---------------------------------------------------------------------------
// kv partials: for (b,h,sc): kvp[d][e] = sum_{s in chunk} k[s,d]*v[s,e],
// ksp[d] = sum k[s,d]. Deterministic split-K, no atomics.
// ---------------------------------------------------------------------------
__global__ __launch_bounds__(512)
void kv_partial(const float* __restrict__ k, const float* __restrict__ v,
                float* __restrict__ kvp, float* __restrict__ ksp)
{
    __shared__ float Ks[32][64];
    __shared__ float Vs[32][64];
    const int t  = threadIdx.x;
    const int bh = blockIdx.x;
    const int b  = bh >> 4;
    const int h  = bh & 15;
    const int sc = blockIdx.y;
    const int d  = t & 63;
    const int e0 = (t >> 6) * 8;

    float acc[8];
#pragma unroll
    for (int j = 0; j < 8; ++j) acc[j] = 0.f;
    float ks = 0.f;

    const size_t rowbase = (size_t)b * SEQ;
    const int sbeg = sc * (SEQ / SCHUNK);       // 256 rows per chunk
    const int send = sbeg + (SEQ / SCHUNK);
    const int lrow = t >> 4;                    // staging: 0..31
    const int lc4  = (t & 15) * 4;

    for (int s0 = sbeg; s0 < send; s0 += 32) {
        const size_t g = (rowbase + s0 + lrow) * DMODEL + h * HDIM + lc4;
        *(float4*)&Ks[lrow][lc4] = *(const float4*)&k[g];
        *(float4*)&Vs[lrow][lc4] = *(const float4*)&v[g];
        __syncthreads();
#pragma unroll 8
        for (int sp = 0; sp < 32; ++sp) {
            const float kd = Ks[sp][d];
            if (t < 64) ks += Ks[sp][t];        // wave 0 only (wave-uniform branch)
            const float4 v0 = *(const float4*)&Vs[sp][e0 + 0];
            const float4 v1 = *(const float4*)&Vs[sp][e0 + 4];
            acc[0] = fmaf(kd, v0.x, acc[0]);  acc[1] = fmaf(kd, v0.y, acc[1]);
            acc[2] = fmaf(kd, v0.z, acc[2]);  acc[3] = fmaf(kd, v0.w, acc[3]);
            acc[4] = fmaf(kd, v1.x, acc[4]);  acc[5] = fmaf(kd, v1.y, acc[5]);
            acc[6] = fmaf(kd, v1.z, acc[6]);  acc[7] = fmaf(kd, v1.w, acc[7]);
        }
        __syncthreads();
    }

    const size_t base = ((size_t)sc * NBH + bh) * HDIM;
    float4 o0; o0.x = acc[0]; o0.y = acc[1]; o0.z = acc[2]; o0.w = acc[3];
    float4 o1; o1.x = acc[4]; o1.y = acc[5]; o1.z = acc[6]; o1.w = acc[7];
    *(float4*)&kvp[(base + d) * HDIM + e0 + 0] = o0;
    *(float4*)&kvp[(base + d) * HDIM + e0 + 4] = o1;
    if (t < 64) ksp[base + t] = ks;
}

__global__ __launch_bounds__(256)
void kv_reduce(const float* __restrict__ kvp, const float* __restrict__ ksp,
               float* __restrict__ kv, float* __restrict__ ksum)
{
    const int i = blockIdx.x * 256 + threadIdx.x;
    const int NKV = NBH * HDIM * HDIM;
    if (i < NKV) {
        float s = 0.f;
#pragma unroll
        for (int c = 0; c < SCHUNK; ++c) s += kvp[(size_t)c * NKV + i];
        kv[i] = s;
    }
    if (i < NBH * HDIM) {
        float s = 0.f;
#pragma unroll
        for (int c = 0; c < SCHUNK; ++c) s += ksp[(size_t)c * NBH * HDIM + i];
        ksum[i] = s;
    }
}

// ---------------------------------------------------------------------------
// att[s,e] = (sum_d q[s,d]*kv[d,e]) / (sum_d q[s,d]*ksum[d] + 1e-6),
// written directly as bf16 hi/lo (fused split for the final GEMM's A-operand).
// ---------------------------------------------------------------------------
__global__ __launch_bounds__(256)
void qkv_norm(const float* __restrict__ q, const float* __restrict__ kv,
              const float* __restrict__ ksum,
              unsigned short* __restrict__ ah, unsigned short* __restrict__ al)
{
    __shared__ float Qs[64][68];
    __shared__ float KVs[64][64];
    __shared__ float kss[64];
    const int t  = threadIdx.x;
    const int s0 = blockIdx.x * 64;
    const int b  = blockIdx.y;
    const int h  = blockIdx.z;
    const int bh = b * NHEAD + h;

#pragma unroll
    for (int i = 0; i < 4; ++i) {
        const int idx = i * 256 + t;
        const int row = idx >> 4;
        const int c4  = (idx & 15) * 4;
        const float4 vq = *(const float4*)&q[((size_t)b * SEQ + s0 + row) * DMODEL + h * HDIM + c4];
        *(float4*)&Qs[row][c4] = vq;
        *(float4*)&((float*)KVs)[idx * 4] = *(const float4*)&kv[(size_t)bh * HDIM * HDIM + idx * 4];
    }
    if (t < 64) kss[t] = ksum[(size_t)bh * HDIM + t];
    __syncthreads();

    const int r  = t >> 2;
    const int e0 = (t & 3) * 16;
    float out[16];
#pragma unroll
    for (int j = 0; j < 16; ++j) out[j] = 0.f;
    float nrm = 0.f;

#pragma unroll 8
    for (int d = 0; d < 64; ++d) {
        const float qd = Qs[r][d];
        nrm = fmaf(qd, kss[d], nrm);
        const float4 k0 = *(const float4*)&KVs[d][e0 + 0];
        const float4 k1 = *(const float4*)&KVs[d][e0 + 4];
        const float4 k2 = *(const float4*)&KVs[d][e0 + 8];
        const float4 k3 = *(const float4*)&KVs[d][e0 + 12];
        out[0]  = fmaf(qd, k0.x, out[0]);  out[1]  = fmaf(qd, k0.y, out[1]);
        out[2]  = fmaf(qd, k0.z, out[2]);  out[3]  = fmaf(qd, k0.w, out[3]);
        out[4]  = fmaf(qd, k1.x, out[4]);  out[5]  = fmaf(qd, k1.y, out[5]);
        out[6]  = fmaf(qd, k1.z, out[6]);  out[7]  = fmaf(qd, k1.w, out[7]);
        out[8]  = fmaf(qd, k2.x, out[8]);  out[9]  = fmaf(qd, k2.y, out[9]);
        out[10] = fmaf(qd, k2.z, out[10]); out[11] = fmaf(qd, k2.w, out[11]);
        out[12] = fmaf(qd, k3.x, out[12]); out[13] = fmaf(qd, k3.y, out[13]);
        out[14] = fmaf(qd, k3.z, out[14]); out[15] = fmaf(qd, k3.w, out[15]);
    }

    const float inv = 1.f / (nrm + 1e-6f);
    const size_t gbase = ((size_t)b * SEQ + s0 + r) * DMODEL + h * HDIM + e0;
#pragma unroll
    for (int g4 = 0; g4 < 4; ++g4) {
        ushort4 H, L;
        const float v0 = out[g4*4+0] * inv;
        const float v1 = out[g4*4+1] * inv;
        const float v2 = out[g4*4+2] * inv;
        const float v3 = out[g4*4+3] * inv;
        H.x = f2bf(v0); L.x = f2bf(v0 - bf2f(H.x));
        H.y = f2bf(v1); L.y = f2bf(v1 - bf2f(H.y));
        H.z = f2bf(v2); L.z = f2bf(v2 - bf2f(H.z));
        H.w = f2bf(v3); L.w = f2bf(v3 - bf2f(H.w));
        *(ushort4*)&ah[gbase + g4 * 4] = H;
        *(ushort4*)&al[gbase + g4 * 4] = L;
    }
}

// ---------------------------------------------------------------------------
extern "C" void kernel_launch(void* const* d_in, const int* in_sizes, int n_in,
                              void* d_out, int out_size, void* d_ws, size_t ws_size,
                              hipStream_t stream)
{
    const float* x  = (const float*)d_in[0];
    const float* Wq = (const float*)d_in[1];
    const float* bq = (const float*)d_in[2];
    const float* Wk = (const float*)d_in[3];
    const float* bk = (const float*)d_in[4];
    const float* Wv = (const float*)d_in[5];
    const float* bv = (const float*)d_in[6];
    const float* Wo = (const float*)d_in[7];
    const float* bo = (const float*)d_in[8];

    // workspace layout (~163 MB):
    unsigned short* xh = (unsigned short*)d_ws;                    // [16384][1024] bf16 hi (x, then att)
    unsigned short* xl = xh + (size_t)NROWS * DMODEL;              // lo
    unsigned short* wsp = xl + (size_t)NROWS * DMODEL;             // 8 x 1M bf16: q_h,q_l,k_h,k_l,v_h,v_l,o_h,o_l
    float* buf0 = (float*)(wsp + 8u * M1);                         // k, then q (fp32)
    float* kv   = buf0 + (size_t)NROWS * DMODEL;                   // [NBH][64][64]
    float* ksum = kv + NBH * HDIM * HDIM;                          // [NBH][64]
    float* kvp  = ksum + NBH * HDIM;                               // [SCHUNK][NBH][64][64]
    float* ksp  = kvp + (size_t)SCHUNK * NBH * HDIM * HDIM;        // [SCHUNK][NBH][64]
    float* vbuf = (float*)d_out;                                   // v lives in d_out (dead before final GEMM)

    const dim3 gg(256);   // (16384/256) x (1024/256) = 64 x 4, flat + XCD swizzle
    const int n4x = NROWS * DMODEL / 4;

    // convert weights + x to bf16 hi/lo
    split_w4<<<dim3(1024, 4), 256, 0, stream>>>(Wq, Wk, Wv, Wo, wsp);
    split_pair<<<4096, 256, 0, stream>>>(x, xh, xl, n4x);
    // k = elu(x@Wk^T + bk)+1 ; v = x@Wv^T + bv
    gemm_split8<1><<<gg, 512, 0, stream>>>(xh, xl, wsp + 2u * M1, wsp + 3u * M1, bk, buf0);
    gemm_split8<0><<<gg, 512, 0, stream>>>(xh, xl, wsp + 4u * M1, wsp + 5u * M1, bv, vbuf);
    // kv, ksum (deterministic split-K + reduce)
    kv_partial<<<dim3(NBH, SCHUNK), 512, 0, stream>>>(buf0, vbuf, kvp, ksp);
    kv_reduce<<<1024, 256, 0, stream>>>(kvp, ksp, kv, ksum);
    // q = elu(x@Wq^T + bq)+1   (overwrites k)
    gemm_split8<1><<<gg, 512, 0, stream>>>(xh, xl, wsp, wsp + M1, bq, buf0);
    // att = (q@kv)/(q@ksum + 1e-6), fused bf16 hi/lo split (x split is dead; reuse xh/xl)
    qkv_norm<<<dim3(SEQ / 64, NBATCH, NHEAD), 256, 0, stream>>>(buf0, kv, ksum, xh, xl);
    // out = att@Wo^T + bo  (overwrites v in d_out)
    gemm_split8<0><<<gg, 512, 0, stream>>>(xh, xl, wsp + 6u * M1, wsp + 7u * M1, bo, (float*)d_out);
}